// Round 5
// baseline (611.412 us; speedup 1.0000x reference)
//
#include <hip/hip_runtime.h>
#include <stdint.h>
#include <stddef.h>

#define B_ 1024
#define S_ 512
#define I_ 64
#define H_ 128
#define G_ 512       // 4H
#define KTOT 192     // I + H
#define ROWS 4       // batch rows per block (256 blocks -> all 256 CUs)
#define RSTRIDE 288  // h row stride bytes: 256 data + 32 pad (72 dw == 8 mod 32 -> 2-way banks)
#define HBUF (ROWS * RSTRIDE)     // 1152 B per h buffer
#define XRSTRIDE 160              // xr row stride bytes: 128 data + 32 pad
#define XRBUF (ROWS * XRSTRIDE)   // 640 B per xr buffer

typedef __bf16 bf16;
typedef __bf16 bf16x8 __attribute__((ext_vector_type(8)));
typedef float f32x4 __attribute__((ext_vector_type(4)));
typedef unsigned short u16;
typedef unsigned short u16x4 __attribute__((ext_vector_type(4)));

// ---- workspace layout (bytes) ---- total ~207 KB (no big intermediates!)
#define WS_WCT  ((size_t)0)                      // bf16 [G][KTOT] = 196,608 B
#define WS_BIAS (WS_WCT + (size_t)G_*KTOT*2)     // f32  [G]
#define WS_M16  (WS_BIAS + (size_t)G_*4)         // bf16 [I][I] (collapsed FFN)
#define WS_CVEC (WS_M16 + (size_t)I_*I_*2)       // f32  [I]

// ---------------------------------------------------------------------------
// Precompute: M16 = bf16(W1*W0) (FFN collapse: no nonlinearity between the
// two Linears, dropout=identity), cvec = b1 + W1*b0, biascat = b_ih+b_hh,
// wct[n][k] = (k<64 ? W_ih[n][k] : W_hh[n][k-64]) as bf16.
// ---------------------------------------------------------------------------
__global__ __launch_bounds__(256) void precompute_kernel(
    const float* __restrict__ W0, const float* __restrict__ b0,
    const float* __restrict__ W1, const float* __restrict__ b1,
    const float* __restrict__ W_ih, const float* __restrict__ W_hh,
    const float* __restrict__ b_ih, const float* __restrict__ b_hh,
    char* __restrict__ ws)
{
  int tid = blockIdx.x * 256 + threadIdx.x;   // grid 64x256 = 16384 threads
  bf16*  m16     = (bf16*)(ws + WS_M16);
  float* cvec    = (float*)(ws + WS_CVEC);
  float* biascat = (float*)(ws + WS_BIAS);
  bf16*  wct     = (bf16*)(ws + WS_WCT);

  if (tid < 4096) {
    int i = tid >> 6, k = tid & 63;
    float acc = 0.f;
    for (int j = 0; j < 256; ++j) acc += W1[i*256 + j] * W0[j*64 + k];
    m16[tid] = (bf16)acc;
  } else if (tid < 4160) {
    int i = tid - 4096;
    float acc = b1[i];
    for (int j = 0; j < 256; ++j) acc += W1[i*256 + j] * b0[j];
    cvec[i] = acc;
  } else if (tid < 4672) {
    int n = tid - 4160;
    biascat[n] = b_ih[n] + b_hh[n];
  }
  for (int e = tid; e < G_*KTOT; e += 16384) {
    int n = e / KTOT, k = e % KTOT;
    float v = (k < I_) ? W_ih[n*I_ + k] : W_hh[n*H_ + (k - I_)];
    wct[e] = (bf16)v;
  }
}

// ---------------------------------------------------------------------------
// Fully fused FFN + LSTM scan + final projection.
// 256 blocks x 512 threads (8 waves); block owns batch rows [4*blk, +4).
//
// Per step (one barrier):
//  * gates g[4(pad16),512] = [xr_s | h_s](4x192) @ wct^T + bias via
//    mfma_f32_16x16x32_bf16 (A rows 4..15 clamped dups; C rows 4..15 unused).
//    Wave w owns gate cols 16w..16w+15 for all four gates i,f,g,o.
//  * waves 0..3 also compute xr(s+1) = relu(x(s+1)@M16^T + cvec + x(s+1))
//    in TRANSPOSED form (A=M16 rows, B=x^T) so valid C cols are batch 0..3
//    and each valid lane writes 4 consecutive xr cols -> one b64 LDS write,
//    no cross-lane shuffle. x(s+1) is register-prefetched 2 steps ahead.
//  * gate redistribution via a tiny per-wave LDS stage (4 masked b128 writes
//    + 4 b32 reads; no ds_bpermute), then dense activations: each lane owns
//    exactly one (hcol,batch) pair -> 10 transcendental instrs per wave.
//  * h and xr ping-pong in padded LDS buffers (2-way banks = free).
// MFMA layout note: A and B fragments are loaded through the same
// (lane>>4,reg)->k map, so any hw k-permutation cancels in the dot product;
// C/D layout (col=lane&15, row=(lane>>4)*4+reg) is the HW-verified one.
// ---------------------------------------------------------------------------
__device__ inline float sigmf(float x) {
  float e = __builtin_amdgcn_exp2f(-1.4426950408889634f * x);
  return __builtin_amdgcn_rcpf(1.f + e);
}
__device__ inline float tanhf_(float x) {            // 2*sigma(2x) - 1
  float e = __builtin_amdgcn_exp2f(-2.8853900817779268f * x);
  float r = __builtin_amdgcn_rcpf(1.f + e);
  return 2.f * r - 1.f;                              // x->-inf: rcp(inf)=0 -> -1
}

__global__ __launch_bounds__(512, 2) void scan_kernel(
    const char* __restrict__ ws, const float* __restrict__ x,
    const float* __restrict__ Wf, const float* __restrict__ bfp,
    float* __restrict__ out)
{
  const bf16*  __restrict__ wct     = (const bf16*)(ws + WS_WCT);
  const float* __restrict__ biascat = (const float*)(ws + WS_BIAS);
  const bf16*  __restrict__ m16     = (const bf16*)(ws + WS_M16);
  const float* __restrict__ cvec    = (const float*)(ws + WS_CVEC);

  __shared__ __align__(16) char h_lds[2 * HBUF];     // ping-pong h (bf16)
  __shared__ __align__(16) char xr_lds[2 * XRBUF];   // ping-pong xr (bf16)
  __shared__ __align__(16) float stageG[8][4][16][4];// per-wave gate stage

  const int tid = threadIdx.x;
  const int w  = tid >> 6;          // wave 0..7
  const int l  = tid & 63;
  const int lr = l & 15;
  const int lg = l >> 4;
  const int ar = lr & (ROWS - 1);   // clamped batch row
  const int wm = w & 3;             // FFN column tile (waves 0..3)
  const int b0 = blockIdx.x * ROWS;

  // zero h(0) (slot 0, incl pad)
  for (int t = tid; t < HBUF/4; t += 512) reinterpret_cast<int*>(h_lds)[t] = 0;

  // ---- resident fragments ----
  bf16x8 wfrag[4][6];               // gate weights: wave w, gate q, k-chunk
  #pragma unroll
  for (int q = 0; q < 4; ++q) {
    int n = q*128 + w*16 + lr;
    #pragma unroll
    for (int kc = 0; kc < 6; ++kc)
      wfrag[q][kc] = *reinterpret_cast<const bf16x8*>(wct + n*KTOT + kc*32 + lg*8);
  }
  float bias[4];
  #pragma unroll
  for (int q = 0; q < 4; ++q) bias[q] = biascat[q*128 + w*16 + lr];

  bf16x8 mfrag[2];                  // FFN A-side: M16 rows n = wm*16+lr
  #pragma unroll
  for (int kc = 0; kc < 2; ++kc)
    mfrag[kc] = *reinterpret_cast<const bf16x8*>(m16 + (wm*16 + lr)*64 + kc*32 + lg*8);
  f32x4 cvec4 = *reinterpret_cast<const f32x4*>(cvec + wm*16 + lg*4);

  // ---- FFN(0) in prologue, then preload x(1) ----
  f32x4 xq0, xq1, xq2, xq3, xres;
  const size_t xrow = ((size_t)(b0 + ar) * S_) * I_;   // batch row base (clamped)
  if (w < 4) {
    const float* bx = x + xrow + 0*I_;                 // s = 0
    xq0 = *reinterpret_cast<const f32x4*>(bx + lg*8);
    xq1 = *reinterpret_cast<const f32x4*>(bx + lg*8 + 4);
    xq2 = *reinterpret_cast<const f32x4*>(bx + 32 + lg*8);
    xq3 = *reinterpret_cast<const f32x4*>(bx + 32 + lg*8 + 4);
    xres = *reinterpret_cast<const f32x4*>(bx + wm*16 + lg*4);

    bf16x8 xf0, xf1;
    #pragma unroll
    for (int j = 0; j < 4; ++j) {
      xf0[j] = (bf16)xq0[j]; xf0[4+j] = (bf16)xq1[j];
      xf1[j] = (bf16)xq2[j]; xf1[4+j] = (bf16)xq3[j];
    }
    f32x4 fa = {0.f, 0.f, 0.f, 0.f};
    fa = __builtin_amdgcn_mfma_f32_16x16x32_bf16(mfrag[0], xf0, fa, 0, 0, 0);
    fa = __builtin_amdgcn_mfma_f32_16x16x32_bf16(mfrag[1], xf1, fa, 0, 0, 0);
    if (lr < ROWS) {            // valid batch cols
      u16x4 pk;
      #pragma unroll
      for (int r = 0; r < 4; ++r) {
        float t = fa[r] + cvec4[r] + xres[r];
        t = t > 0.f ? t : 0.f;
        pk[r] = __builtin_bit_cast(u16, (bf16)t);
      }
      *reinterpret_cast<u16x4*>(xr_lds + lr*XRSTRIDE + (wm*16 + lg*4)*2) = pk;
    }
    // preload x(1) for FFN(1)
    const float* b1x = x + xrow + 1*I_;
    xq0 = *reinterpret_cast<const f32x4*>(b1x + lg*8);
    xq1 = *reinterpret_cast<const f32x4*>(b1x + lg*8 + 4);
    xq2 = *reinterpret_cast<const f32x4*>(b1x + 32 + lg*8);
    xq3 = *reinterpret_cast<const f32x4*>(b1x + 32 + lg*8 + 4);
    xres = *reinterpret_cast<const f32x4*>(b1x + wm*16 + lg*4);
  }

  float c1 = 0.f;                  // cell state: lane owns (hcol=w*16+lr, b=lg)
  __syncthreads();

  for (int s = 0; s < S_; ++s) {
    // ---- issue x(s+2) prefetch (full step of latency slack) ----
    f32x4 nq0, nq1, nq2, nq3, nres;
    if (w < 4) {
      int sn2 = (s + 2 < S_) ? s + 2 : S_ - 1;
      const float* bx = x + xrow + (size_t)sn2 * I_;
      nq0 = *reinterpret_cast<const f32x4*>(bx + lg*8);
      nq1 = *reinterpret_cast<const f32x4*>(bx + lg*8 + 4);
      nq2 = *reinterpret_cast<const f32x4*>(bx + 32 + lg*8);
      nq3 = *reinterpret_cast<const f32x4*>(bx + 32 + lg*8 + 4);
      nres = *reinterpret_cast<const f32x4*>(bx + wm*16 + lg*4);
    }

    const char* rbh = h_lds  + ((s & 1) ? HBUF  : 0);
    char*       wbh = h_lds  + ((s & 1) ? 0     : HBUF);
    const char* rbx = xr_lds + ((s & 1) ? XRBUF : 0);
    char*       wbx = xr_lds + ((s & 1) ? 0     : XRBUF);

    // ---- A fragments: xr(s) and h(s) from LDS (padded, conflict-free) ----
    bf16x8 axr[2], ah[4];
    #pragma unroll
    for (int kc = 0; kc < 2; ++kc)
      axr[kc] = *reinterpret_cast<const bf16x8*>(rbx + ar*XRSTRIDE + kc*64 + lg*16);
    #pragma unroll
    for (int kc = 0; kc < 4; ++kc)
      ah[kc] = *reinterpret_cast<const bf16x8*>(rbh + ar*RSTRIDE + kc*64 + lg*16);

    // ---- gates: 24 MFMAs/wave ----
    f32x4 acc[4];
    #pragma unroll
    for (int q = 0; q < 4; ++q) {
      acc[q] = (f32x4){bias[q], bias[q], bias[q], bias[q]};
      acc[q] = __builtin_amdgcn_mfma_f32_16x16x32_bf16(axr[0], wfrag[q][0], acc[q], 0, 0, 0);
      acc[q] = __builtin_amdgcn_mfma_f32_16x16x32_bf16(axr[1], wfrag[q][1], acc[q], 0, 0, 0);
      #pragma unroll
      for (int kc = 0; kc < 4; ++kc)
        acc[q] = __builtin_amdgcn_mfma_f32_16x16x32_bf16(ah[kc], wfrag[q][2+kc], acc[q], 0, 0, 0);
    }

    // ---- waves 0..3: FFN for xr(s+1) (hides gate-MFMA latency) ----
    if (w < 4) {
      bf16x8 xf0, xf1;
      #pragma unroll
      for (int j = 0; j < 4; ++j) {
        xf0[j] = (bf16)xq0[j]; xf0[4+j] = (bf16)xq1[j];
        xf1[j] = (bf16)xq2[j]; xf1[4+j] = (bf16)xq3[j];
      }
      f32x4 fa = {0.f, 0.f, 0.f, 0.f};
      fa = __builtin_amdgcn_mfma_f32_16x16x32_bf16(mfrag[0], xf0, fa, 0, 0, 0);
      fa = __builtin_amdgcn_mfma_f32_16x16x32_bf16(mfrag[1], xf1, fa, 0, 0, 0);
      if (lr < ROWS) {
        u16x4 pk;
        #pragma unroll
        for (int r = 0; r < 4; ++r) {
          float t = fa[r] + cvec4[r] + xres[r];
          t = t > 0.f ? t : 0.f;
          pk[r] = __builtin_bit_cast(u16, (bf16)t);
        }
        *reinterpret_cast<u16x4*>(wbx + lr*XRSTRIDE + (wm*16 + lg*4)*2) = pk;
      }
    }

    // ---- redistribute gates via per-wave LDS stage (no bpermute) ----
    if (l < 16) {
      #pragma unroll
      for (int q = 0; q < 4; ++q)
        *reinterpret_cast<f32x4*>(&stageG[w][q][l][0]) = acc[q];
    }
    float g4[4];
    #pragma unroll
    for (int q = 0; q < 4; ++q) g4[q] = stageG[w][q][lr][lg];

    // ---- dense activations: lane owns (hcol=w*16+lr, batch=lg) ----
    float ii = sigmf(g4[0]);
    float ff = sigmf(g4[1]);
    float gg = tanhf_(g4[2]);
    float oo = sigmf(g4[3]);
    float cn = ff * c1 + ii * gg;
    c1 = cn;
    float hn = oo * tanhf_(cn);
    *reinterpret_cast<bf16*>(wbh + lg*RSTRIDE + (w*16 + lr)*2) = (bf16)hn;

    __syncthreads();                 // single barrier per step
    if (w < 4) { xq0=nq0; xq1=nq1; xq2=nq2; xq3=nq3; xres=nres; }
  }

  // ---- final projection: out[b0+row] = h_T[row] . Wf + bf ----
  // step 511 wrote slot 0. One wave: lane (lg,lr): row=lg, cols lr*8..+7.
  if (tid < 64) {
    int row = lg, cl = lr * 8;
    bf16x8 hv = *reinterpret_cast<const bf16x8*>(h_lds + row*RSTRIDE + cl*2);
    float accf = 0.f;
    #pragma unroll
    for (int j = 0; j < 8; ++j) accf += (float)hv[j] * Wf[cl + j];
    accf += __shfl_xor(accf, 1, 64);
    accf += __shfl_xor(accf, 2, 64);
    accf += __shfl_xor(accf, 4, 64);
    accf += __shfl_xor(accf, 8, 64);
    if (lr == 0) out[b0 + row] = accf + bfp[0];
  }
}

// ---------------------------------------------------------------------------
extern "C" void kernel_launch(void* const* d_in, const int* in_sizes, int n_in,
                              void* d_out, int out_size, void* d_ws, size_t ws_size,
                              hipStream_t stream)
{
  const float* x    = (const float*)d_in[0];
  const float* W0   = (const float*)d_in[1];
  const float* b0   = (const float*)d_in[2];
  const float* W1   = (const float*)d_in[3];
  const float* b1   = (const float*)d_in[4];
  const float* W_ih = (const float*)d_in[5];
  const float* W_hh = (const float*)d_in[6];
  const float* b_ih = (const float*)d_in[7];
  const float* b_hh = (const float*)d_in[8];
  const float* Wf   = (const float*)d_in[9];
  const float* bf   = (const float*)d_in[10];
  char* ws = (char*)d_ws;
  float* out = (float*)d_out;

  hipLaunchKernelGGL(precompute_kernel, dim3(64), dim3(256), 0, stream,
                     W0, b0, W1, b1, W_ih, W_hh, b_ih, b_hh, ws);
  hipLaunchKernelGGL(scan_kernel, dim3(256), dim3(512), 0, stream,
                     ws, x, Wf, bf, out);
}